// Round 8
// baseline (451.611 us; speedup 1.0000x reference)
//
#include <hip/hip_runtime.h>
#include <hip/hip_bf16.h>

#define EMBED 1024
#define HEADS 16
#define HD    64
#define NB    4
#define SEQ   2048
#define NBLK  512

typedef __bf16 bf16x2 __attribute__((ext_vector_type(2)));
typedef __bf16 bf16x8 __attribute__((ext_vector_type(8)));
typedef float  f32x4  __attribute__((ext_vector_type(4)));
typedef float  f32x16 __attribute__((ext_vector_type(16)));
typedef unsigned uint2v __attribute__((ext_vector_type(2)));

__device__ __forceinline__ unsigned short f2bf(float f) {
    union { float f; unsigned u; } v; v.f = f;
    unsigned r = v.u + 0x7fffu + ((v.u >> 16) & 1u);   // RNE, inputs finite
    return (unsigned short)(r >> 16);
}
// packed 2xf32 -> bf16x2 (low=a, high=b)
__device__ __forceinline__ unsigned pack2(float a, float b) {
#if __has_builtin(__builtin_amdgcn_cvt_pk_bf16_f32)
    union { bf16x2 v; unsigned u; } c;
    c.v = __builtin_amdgcn_cvt_pk_bf16_f32(a, b);
    return c.u;
#else
    return (unsigned)f2bf(a) | ((unsigned)f2bf(b) << 16);
#endif
}

// Manual grid barrier (non-cooperative; graph-capture safe).
// Preconditions: all NBLK blocks co-resident (2/CU at 46KB LDS, 16 waves/CU);
// cnt/gen zeroed before launch (hipMemsetAsync in kernel_launch, captured).
// __syncthreads drains each thread's vmcnt (stores visible in L2) before the
// lane-0 release fence (buffer_wbl2, device scope).  Acquire fence (buffer_inv)
// before any thread reads.  Bounded spin: on co-residency failure we produce a
// wrong answer instead of a hung container.
__device__ __forceinline__ void grid_barrier(unsigned* cnt, unsigned* gen, unsigned phase) {
    __syncthreads();
    if (threadIdx.x == 0) {
        __threadfence();                         // release (device scope)
        unsigned prev = atomicAdd(cnt, 1u);      // device-scope RMW
        if (prev == NBLK * (phase + 1) - 1) {
            __hip_atomic_store(gen, phase + 1, __ATOMIC_RELEASE, __HIP_MEMORY_SCOPE_AGENT);
        } else {
            long long spins = 0;
            while (__hip_atomic_load(gen, __ATOMIC_ACQUIRE, __HIP_MEMORY_SCOPE_AGENT) < phase + 1) {
                __builtin_amdgcn_s_sleep(2);
                if (++spins > (1LL << 22)) break;   // safety valve: fail, don't hang
            }
        }
        __threadfence();                         // acquire (invalidate L1/L2)
    }
    __syncthreads();
}

// =====================================================================
// Fully fused pipeline: ONE dispatch, 512 blocks x 512 threads, 46.1 KB LDS
// (2 blocks/CU co-resident; LDS would allow 3 -> residency margin).
//   P0 cvt   : Wo fp32 -> bf16
//   P1 proj  : Q/K/V projections, 3 tiles/block
//   ---- grid_barrier(0) ----
//   P2 attn  : round-0 flash-attention body (blocks map 1:1)
//   ---- grid_barrier(1) ----
//   P3 outproj: 128x128 single-buffer GEMM (blocks map 1:1)
// Removes 3 dispatch boundaries (launch latency + per-dispatch L2
// flush/invalidate), the dominant non-kernel cost.
// =====================================================================
__global__ __launch_bounds__(512, 4) void mega_kernel(
    const float* __restrict__ values, const float* __restrict__ keys,
    const float* __restrict__ query,
    const float* __restrict__ Wv, const float* __restrict__ Wk,
    const float* __restrict__ Wq,
    const float* __restrict__ Wo, const float* __restrict__ bo,
    unsigned short* __restrict__ Qp, unsigned short* __restrict__ Kp,
    unsigned short* __restrict__ Vt, unsigned short* __restrict__ Xa,
    unsigned short* __restrict__ Wb, float* __restrict__ out)
{
    __shared__ __align__(16) unsigned short SMEM[23040];   // 46,080 B
    unsigned* bar = (unsigned*)(out + (size_t)NB * SEQ * EMBED - 2);  // cnt, gen (zeroed per launch)

    int bx = blockIdx.x;
    int tid = threadIdx.x;

    // ---------------- P0: cvt Wo -> bf16 --------------------------------
    {
        int i = bx * 512 + tid;              // 512*512*4 = 1,048,576 elems
        float4 v = ((const float4*)Wo)[i];
        uint2 o;
        o.x = pack2(v.x, v.y);
        o.y = pack2(v.z, v.w);
        ((uint2*)Wb)[i] = o;
    }

    // ---------------- P1: Q/K/V projections (3 tiles/block) -------------
    {
        unsigned short* Wl = SMEM;           // 64*72 shorts
        unsigned short* Xl = SMEM + 4608;    // 256*72 shorts
        int w = tid >> 6, lane = tid & 63, ln = lane & 15, qd = lane >> 4;

        for (int t = 0; t < 3; ++t) {
            int id = bx * 3 + t;             // 0..1535
            int p = id >> 9, r = id & 511;
            int st = r & 7, h = (r >> 3) & 15, n = r >> 7;
            int s0 = st * 256;
            const float* x = (p == 0) ? query : (p == 1) ? keys : values;
            const float* W = (p == 0) ? Wq : (p == 1) ? Wk : Wv;
            const float sc = (p == 0) ? 0.045084220027780106f : 1.0f;  // log2(e)/32

            __syncthreads();                 // prior tile's LDS fully consumed
#pragma unroll
            for (int i2 = 0; i2 < 2; ++i2) {
                int idx = tid + i2 * 512;
                int row = idx >> 4, c4 = idx & 15;
                float4 wv = ((const float4*)W)[row * 16 + c4];
                uint2 pw;
                pw.x = pack2(wv.x, wv.y);
                pw.y = pack2(wv.z, wv.w);
                *(uint2*)&Wl[row * 72 + c4 * 4] = pw;
            }
            const float* xbase = x + (size_t)(n * SEQ + s0) * EMBED + h * HD;
#pragma unroll
            for (int i2 = 0; i2 < 8; ++i2) {
                int idx = tid + i2 * 512;
                int row = idx >> 4, c4 = idx & 15;
                float4 v = *(const float4*)(xbase + (size_t)row * EMBED + c4 * 4);
                uint2 px;
                px.x = pack2(v.x, v.y);
                px.y = pack2(v.z, v.w);
                *(uint2*)&Xl[row * 72 + c4 * 4] = px;
            }
            __syncthreads();

            // wave w owns s-rows w*32..w*32+31
            bf16x8 a[2][2], b[4][2];
#pragma unroll
            for (int mt = 0; mt < 2; ++mt)
#pragma unroll
                for (int kt = 0; kt < 2; ++kt)
                    a[mt][kt] = *(const bf16x8*)&Xl[(w * 32 + mt * 16 + ln) * 72 + kt * 32 + qd * 8];
#pragma unroll
            for (int i2 = 0; i2 < 4; ++i2)
#pragma unroll
                for (int kt = 0; kt < 2; ++kt)
                    b[i2][kt] = *(const bf16x8*)&Wl[(i2 * 16 + ln) * 72 + kt * 32 + qd * 8];

            f32x4 acc[4][2];
            const f32x4 fz = {0.f, 0.f, 0.f, 0.f};
#pragma unroll
            for (int i2 = 0; i2 < 4; ++i2)
#pragma unroll
                for (int j = 0; j < 2; ++j) acc[i2][j] = fz;

            if (p < 2) {
#pragma unroll
                for (int i2 = 0; i2 < 4; ++i2)
#pragma unroll
                    for (int j = 0; j < 2; ++j) {
                        acc[i2][j] = __builtin_amdgcn_mfma_f32_16x16x32_bf16(b[i2][0], a[j][0], acc[i2][j], 0, 0, 0);
                        acc[i2][j] = __builtin_amdgcn_mfma_f32_16x16x32_bf16(b[i2][1], a[j][1], acc[i2][j], 0, 0, 0);
                    }
                // each wave writes only its own rows -> no cross-wave hazard
#pragma unroll
                for (int i2 = 0; i2 < 4; ++i2)
#pragma unroll
                    for (int j = 0; j < 2; ++j) {
                        uint2 pk;
                        pk.x = pack2(acc[i2][j][0] * sc, acc[i2][j][1] * sc);
                        pk.y = pack2(acc[i2][j][2] * sc, acc[i2][j][3] * sc);
                        *(uint2*)&Xl[(w * 32 + j * 16 + ln) * 72 + i2 * 16 + qd * 4] = pk;
                    }
                __syncthreads();
                unsigned short* outp = (p == 0 ? Qp : Kp) + (size_t)(n * HEADS + h) * SEQ * HD + (size_t)s0 * HD;
#pragma unroll
                for (int i2 = 0; i2 < 4; ++i2) {
                    int idx = tid + i2 * 512;          // 2048 uint4
                    int row = idx >> 3, ch = idx & 7;
                    *(uint4*)(outp + (size_t)row * HD + ch * 8) = *(const uint4*)&Xl[row * 72 + ch * 8];
                }
            } else {
                // V: transposed output [d][s]
#pragma unroll
                for (int mt = 0; mt < 2; ++mt)
#pragma unroll
                    for (int i2 = 0; i2 < 4; ++i2) {
                        acc[i2][mt] = __builtin_amdgcn_mfma_f32_16x16x32_bf16(a[mt][0], b[i2][0], acc[i2][mt], 0, 0, 0);
                        acc[i2][mt] = __builtin_amdgcn_mfma_f32_16x16x32_bf16(a[mt][1], b[i2][1], acc[i2][mt], 0, 0, 0);
                    }
                __syncthreads();             // transposed writes span all rows
#pragma unroll
                for (int mt = 0; mt < 2; ++mt)
#pragma unroll
                    for (int i2 = 0; i2 < 4; ++i2) {
                        uint2 pk;
                        pk.x = pack2(acc[i2][mt][0], acc[i2][mt][1]);
                        pk.y = pack2(acc[i2][mt][2], acc[i2][mt][3]);
                        *(uint2*)&Xl[(i2 * 16 + ln) * 264 + w * 32 + mt * 16 + qd * 4] = pk;
                    }
                __syncthreads();
                unsigned short* outp = Vt + (size_t)(n * HEADS + h) * HD * SEQ + s0;
#pragma unroll
                for (int i2 = 0; i2 < 4; ++i2) {
                    int idx = tid + i2 * 512;          // 2048 uint4
                    int row = idx >> 5, ch = idx & 31;
                    *(uint4*)(outp + (size_t)row * SEQ + ch * 8) = *(const uint4*)&Xl[row * 264 + ch * 8];
                }
            }
        }
    }

    grid_barrier(bar, bar + 1, 0);

    // ---------------- P2: flash attention (round-0 body) ----------------
    {
        unsigned short* Kl = SMEM;           // [2][64*72]  (key, d)
        unsigned short* Vl = SMEM + 9216;    // [2][64*72]  (d, key)

        int head = bx >> 3, qt = bx & 7;
        int n = head >> 4, h16 = head & 15;
        int q0 = qt * 256;

        int w = tid >> 6, lane = tid & 63;
        int qc = lane & 31, hh = lane >> 5;

        const unsigned short* Qb = Qp + (size_t)head * SEQ * HD;
        const unsigned short* Kb = Kp + (size_t)head * SEQ * HD;
        const unsigned short* Vb = Vt + (size_t)head * HD * SEQ;

        bf16x8 qb[4];
        {
            int qrow = q0 + w * 32 + qc;
#pragma unroll
            for (int kk = 0; kk < 4; ++kk)
                qb[kk] = *(const bf16x8*)(Qb + (size_t)qrow * HD + kk * 16 + hh * 8);
        }

        f32x16 ot0, ot1;
#pragma unroll
        for (int i = 0; i < 16; ++i) { ot0[i] = 0.f; ot1[i] = 0.f; }
        float ls[4] = {0.f, 0.f, 0.f, 0.f};

        int srow = tid >> 3, sch = tid & 7;

        uint4 rK, rV;
        rK = *(const uint4*)(Kb + (size_t)srow * HD + sch * 8);
        rV = *(const uint4*)(Vb + (size_t)srow * SEQ + 0 + sch * 8);
        *(uint4*)&Kl[srow * 72 + sch * 8] = rK;
        *(uint4*)&Vl[srow * 72 + sch * 8] = rV;
        rK = *(const uint4*)(Kb + (size_t)(64 + srow) * HD + sch * 8);
        rV = *(const uint4*)(Vb + (size_t)srow * SEQ + 64 + sch * 8);

        for (int kc = 0; kc < SEQ; kc += 64) {
            int cur = (kc >> 6) & 1, nxt = cur ^ 1;
            int curo = cur * 4608;
            __syncthreads();

            if (kc + 64 < SEQ) {
                *(uint4*)&Kl[nxt * 4608 + srow * 72 + sch * 8] = rK;
                *(uint4*)&Vl[nxt * 4608 + srow * 72 + sch * 8] = rV;
                int kn = kc + 128 <= SEQ - 64 ? kc + 128 : SEQ - 64;
                rK = *(const uint4*)(Kb + (size_t)(kn + srow) * HD + sch * 8);
                rV = *(const uint4*)(Vb + (size_t)srow * SEQ + kn + sch * 8);
            }

            unsigned pk[2][8];
#pragma unroll
            for (int kt = 0; kt < 2; ++kt) {
                f32x16 c;
#pragma unroll
                for (int i = 0; i < 16; ++i) c[i] = 0.f;
#pragma unroll
                for (int kk = 0; kk < 4; ++kk) {
                    bf16x8 ka = *(const bf16x8*)&Kl[curo + (kt * 32 + qc) * 72 + kk * 16 + hh * 8];
                    c = __builtin_amdgcn_mfma_f32_32x32x16_bf16(ka, qb[kk], c, 0, 0, 0);
                }
#pragma unroll
                for (int i = 0; i < 8; ++i) {
                    float p0 = __builtin_amdgcn_exp2f(c[2 * i]);
                    float p1 = __builtin_amdgcn_exp2f(c[2 * i + 1]);
                    ls[i & 3] += p0 + p1;
                    pk[kt][i] = pack2(p0, p1);
                }
            }

#pragma unroll
            for (int g = 0; g < 4; ++g) {
                const unsigned* P = pk[g >> 1];
                int base = (g & 1) * 4;
                union { unsigned u[4]; bf16x8 v; } bb;
#if __has_builtin(__builtin_amdgcn_permlane32_swap)
                uint2v rr0 = __builtin_amdgcn_permlane32_swap(P[base + 0], P[base + 2], false, false);
                uint2v rr1 = __builtin_amdgcn_permlane32_swap(P[base + 1], P[base + 3], false, false);
                bb.u[0] = rr0.x;
                bb.u[1] = rr1.x;
                bb.u[2] = rr0.y;
                bb.u[3] = rr1.y;
#else
                unsigned s0_ = hh ? P[base + 0] : P[base + 2];
                unsigned s1_ = hh ? P[base + 1] : P[base + 3];
                unsigned r0_ = (unsigned)__shfl_xor((int)s0_, 32);
                unsigned r1_ = (unsigned)__shfl_xor((int)s1_, 32);
                bb.u[0] = hh ? r0_ : P[base + 0];
                bb.u[1] = hh ? r1_ : P[base + 1];
                bb.u[2] = hh ? P[base + 2] : r0_;
                bb.u[3] = hh ? P[base + 3] : r1_;
#endif
                bf16x8 va0 = *(const bf16x8*)&Vl[curo + qc * 72 + g * 16 + hh * 8];
                bf16x8 va1 = *(const bf16x8*)&Vl[curo + (32 + qc) * 72 + g * 16 + hh * 8];
                ot0 = __builtin_amdgcn_mfma_f32_32x32x16_bf16(va0, bb.v, ot0, 0, 0, 0);
                ot1 = __builtin_amdgcn_mfma_f32_32x32x16_bf16(va1, bb.v, ot1, 0, 0, 0);
            }
        }

        float lsum = (ls[0] + ls[1]) + (ls[2] + ls[3]);
        lsum += __shfl_xor(lsum, 32);
        float inv = 1.0f / lsum;

        __syncthreads();
        int qlocal = w * 32 + qc;
#pragma unroll
        for (int dt = 0; dt < 2; ++dt) {
            const f32x16& o = dt ? ot1 : ot0;
#pragma unroll
            for (int g = 0; g < 4; ++g) {
                uint2 p;
                p.x = pack2(o[4 * g + 0] * inv, o[4 * g + 1] * inv);
                p.y = pack2(o[4 * g + 2] * inv, o[4 * g + 3] * inv);
                *(uint2*)&SMEM[qlocal * 72 + dt * 32 + g * 8 + hh * 4] = p;
            }
        }
        __syncthreads();
        unsigned short* ob = Xa + (size_t)(n * SEQ + q0) * EMBED + h16 * HD;
#pragma unroll
        for (int i = 0; i < 4; ++i) {
            int idx = tid + i * 512;
            int row = idx >> 3, ch = idx & 7;
            *(uint4*)(ob + (size_t)row * EMBED + ch * 8) = *(const uint4*)&SMEM[row * 72 + ch * 8];
        }
    }

    grid_barrier(bar, bar + 1, 1);

    // ---------------- P3: out = Xa @ Wo^T + bo (128x128, single buffer) --
    {
        unsigned short* Al = SMEM;               // 128*72
        unsigned short* Bl = SMEM + 9216;        // 128*72

        int cm = bx >> 3, cn = bx & 7;
        int m0 = cm * 128, c0 = cn * 128;
        int w = tid >> 6, lane = tid & 63, ln = lane & 15, qd = lane >> 4;
        int wr = w >> 2, wc = w & 3;             // wave tile: rows wr*64, cols wc*32

        int r1 = tid >> 3, ch = tid & 7;
        const unsigned short* Xb = Xa + (size_t)(m0 + r1) * EMBED + ch * 8;
        const unsigned short* Wbb = Wb + (size_t)(c0 + r1) * EMBED + ch * 8;

        f32x4 acc[4][2];
        const f32x4 fz = {0.f, 0.f, 0.f, 0.f};
#pragma unroll
        for (int mt = 0; mt < 4; ++mt)
#pragma unroll
            for (int nt = 0; nt < 2; ++nt) acc[mt][nt] = fz;

        for (int k0 = 0; k0 < EMBED; k0 += 64) {
            __syncthreads();                     // prior K-step's LDS reads done
            *(uint4*)&Al[r1 * 72 + ch * 8]        = *(const uint4*)(Xb + k0);
            *(uint4*)&Al[(r1 + 64) * 72 + ch * 8] = *(const uint4*)(Xb + (size_t)64 * EMBED + k0);
            *(uint4*)&Bl[r1 * 72 + ch * 8]        = *(const uint4*)(Wbb + k0);
            *(uint4*)&Bl[(r1 + 64) * 72 + ch * 8] = *(const uint4*)(Wbb + (size_t)64 * EMBED + k0);
            __syncthreads();

            bf16x8 af[4][2], bf_[2][2];
#pragma unroll
            for (int mt = 0; mt < 4; ++mt)
#pragma unroll
                for (int kt = 0; kt < 2; ++kt)
                    af[mt][kt] = *(const bf16x8*)&Al[(wr * 64 + mt * 16 + ln) * 72 + kt * 32 + qd * 8];
#pragma unroll
            for (int nt = 0; nt < 2; ++nt)
#pragma unroll
                for (int kt = 0; kt < 2; ++kt)
                    bf_[nt][kt] = *(const bf16x8*)&Bl[(wc * 32 + nt * 16 + ln) * 72 + kt * 32 + qd * 8];
#pragma unroll
            for (int mt = 0; mt < 4; ++mt)
#pragma unroll
                for (int nt = 0; nt < 2; ++nt) {
                    acc[mt][nt] = __builtin_amdgcn_mfma_f32_16x16x32_bf16(af[mt][0], bf_[nt][0], acc[mt][nt], 0, 0, 0);
                    acc[mt][nt] = __builtin_amdgcn_mfma_f32_16x16x32_bf16(af[mt][1], bf_[nt][1], acc[mt][nt], 0, 0, 0);
                }
        }

#pragma unroll
        for (int nt = 0; nt < 2; ++nt) {
            int col = c0 + wc * 32 + nt * 16 + ln;
            float bias = bo[col];
#pragma unroll
            for (int mt = 0; mt < 4; ++mt) {
                int row = m0 + wr * 64 + mt * 16 + qd * 4;
#pragma unroll
                for (int rg = 0; rg < 4; ++rg)
                    out[(size_t)(row + rg) * EMBED + col] = acc[mt][nt][rg] + bias;
            }
        }
    }
}

// --------------------------------------------------------------------- launch
extern "C" void kernel_launch(void* const* d_in, const int* in_sizes, int n_in,
                              void* d_out, int out_size, void* d_ws, size_t ws_size,
                              hipStream_t stream) {
    const float* values = (const float*)d_in[0];
    const float* keys   = (const float*)d_in[1];
    const float* query  = (const float*)d_in[2];
    const float* Wv     = (const float*)d_in[3];
    const float* Wk     = (const float*)d_in[4];
    const float* Wq     = (const float*)d_in[5];
    const float* Wo     = (const float*)d_in[6];
    const float* bo     = (const float*)d_in[7];
    float* out = (float*)d_out;

    unsigned short* ws = (unsigned short*)d_ws;
    const size_t HSZ = (size_t)NB * HEADS * SEQ * HD;   // 8388608 elems
    unsigned short* Qp = ws;
    unsigned short* Kp = Qp + HSZ;
    unsigned short* Vt = Kp + HSZ;
    unsigned short* Xa = Vt + HSZ;
    unsigned short* Wb = Xa + HSZ;                       // 1024*1024 elems

    // zero the barrier state (last 8 bytes of out) — captured, re-runs each replay
    hipMemsetAsync(out + (size_t)NB * SEQ * EMBED - 2, 0, 8, stream);
    mega_kernel<<<NBLK, 512, 0, stream>>>(values, keys, query, Wv, Wk, Wq, Wo, bo,
                                          Qp, Kp, Vt, Xa, Wb, out);
}

// Round 9
// 264.534 us; speedup vs baseline: 1.7072x; 1.7072x over previous
//
#include <hip/hip_runtime.h>
#include <hip/hip_bf16.h>

#define EMBED 1024
#define HEADS 16
#define HD    64
#define NB    4
#define SEQ   2048

typedef __bf16 bf16x2 __attribute__((ext_vector_type(2)));
typedef __bf16 bf16x8 __attribute__((ext_vector_type(8)));
typedef float  f32x4  __attribute__((ext_vector_type(4)));
typedef float  f32x16 __attribute__((ext_vector_type(16)));
typedef unsigned uint2v __attribute__((ext_vector_type(2)));

__device__ __forceinline__ unsigned short f2bf(float f) {
    union { float f; unsigned u; } v; v.f = f;
    unsigned r = v.u + 0x7fffu + ((v.u >> 16) & 1u);   // RNE, inputs finite
    return (unsigned short)(r >> 16);
}
// packed 2xf32 -> bf16x2 (low=a, high=b)
__device__ __forceinline__ unsigned pack2(float a, float b) {
#if __has_builtin(__builtin_amdgcn_cvt_pk_bf16_f32)
    union { bf16x2 v; unsigned u; } c;
    c.v = __builtin_amdgcn_cvt_pk_bf16_f32(a, b);
    return c.u;
#else
    return (unsigned)f2bf(a) | ((unsigned)f2bf(b) << 16);
#endif
}

// ------------------------------------------------------- Q/K/V projections
// Blocks 0..1535: 256 s-rows per block.  p=0: query@Wq^T (scale log2(e)/32
// folded) -> Qp [h][s][d]   p=1: keys@Wk^T -> Kp   p=2: values@Wv^T -> Vt.
// Blocks 1536..1791: cvt tail — Wo fp32 -> bf16 (each element exactly once);
// folds the old cvt_kernel dispatch into this launch.
__global__ __launch_bounds__(256) void proj_kernel(
    const float* __restrict__ xq, const float* __restrict__ xk, const float* __restrict__ xv,
    const float* __restrict__ Wq, const float* __restrict__ Wk, const float* __restrict__ Wv,
    const float* __restrict__ Wo, unsigned* __restrict__ Wb,
    unsigned short* __restrict__ Qp, unsigned short* __restrict__ Kp, unsigned short* __restrict__ Vt)
{
    __shared__ __align__(16) unsigned short Wl[64 * 72];
    __shared__ __align__(16) unsigned short Xl[256 * 72];

    int bx = blockIdx.x;                  // 1792 = 3*512 proj + 256 cvt
    int tid = threadIdx.x;

    if (bx >= 1536) {                     // ---- cvt tail: Wo -> bf16 ----
        int base = (bx - 1536) * 1024;    // 256 blocks x 1024 float4
#pragma unroll
        for (int t = 0; t < 4; ++t) {
            int i = base + t * 256 + tid;
            float4 v = ((const float4*)Wo)[i];
            uint2 o;
            o.x = pack2(v.x, v.y);
            o.y = pack2(v.z, v.w);
            ((uint2*)Wb)[i] = o;
        }
        return;                           // no barriers executed: block-uniform exit
    }

    int p  = bx >> 9;
    int r  = bx & 511;
    int st = r & 7, h = (r >> 3) & 15, n = r >> 7;
    int s0 = st * 256;

    const float* x = (p == 0) ? xq : (p == 1) ? xk : xv;
    const float* W = (p == 0) ? Wq : (p == 1) ? Wk : Wv;
    const float sc = (p == 0) ? 0.045084220027780106f : 1.0f;  // log2(e)/32

    for (int i = 0; i < 4; ++i) {
        int idx = tid + i * 256;
        int row = idx >> 4, c4 = idx & 15;
        float4 wv = ((const float4*)W)[row * 16 + c4];
        uint2 pw;
        pw.x = pack2(wv.x, wv.y);
        pw.y = pack2(wv.z, wv.w);
        *(uint2*)&Wl[row * 72 + c4 * 4] = pw;
    }
    const float* xbase = x + (size_t)(n * SEQ + s0) * EMBED + h * HD;
    for (int i = 0; i < 16; ++i) {
        int idx = tid + i * 256;
        int row = idx >> 4, c4 = idx & 15;
        float4 v = *(const float4*)(xbase + (size_t)row * EMBED + c4 * 4);
        uint2 px;
        px.x = pack2(v.x, v.y);
        px.y = pack2(v.z, v.w);
        *(uint2*)&Xl[row * 72 + c4 * 4] = px;
    }
    __syncthreads();

    int w = tid >> 6, lane = tid & 63, ln = lane & 15, qd = lane >> 4;

    bf16x8 a[4][2], b[4][2];
#pragma unroll
    for (int mt = 0; mt < 4; ++mt)
#pragma unroll
        for (int kt = 0; kt < 2; ++kt)
            a[mt][kt] = *(const bf16x8*)&Xl[(w * 64 + mt * 16 + ln) * 72 + kt * 32 + qd * 8];
#pragma unroll
    for (int i = 0; i < 4; ++i)
#pragma unroll
        for (int kt = 0; kt < 2; ++kt)
            b[i][kt] = *(const bf16x8*)&Wl[(i * 16 + ln) * 72 + kt * 32 + qd * 8];

    f32x4 acc[4][4];
    const f32x4 fz = {0.f, 0.f, 0.f, 0.f};
#pragma unroll
    for (int i = 0; i < 4; ++i)
#pragma unroll
        for (int j = 0; j < 4; ++j) acc[i][j] = fz;

    if (p < 2) {
#pragma unroll
        for (int i = 0; i < 4; ++i)
#pragma unroll
            for (int j = 0; j < 4; ++j) {
                acc[i][j] = __builtin_amdgcn_mfma_f32_16x16x32_bf16(b[i][0], a[j][0], acc[i][j], 0, 0, 0);
                acc[i][j] = __builtin_amdgcn_mfma_f32_16x16x32_bf16(b[i][1], a[j][1], acc[i][j], 0, 0, 0);
            }
#pragma unroll
        for (int i = 0; i < 4; ++i)
#pragma unroll
            for (int j = 0; j < 4; ++j) {
                uint2 pk;
                pk.x = pack2(acc[i][j][0] * sc, acc[i][j][1] * sc);
                pk.y = pack2(acc[i][j][2] * sc, acc[i][j][3] * sc);
                *(uint2*)&Xl[(w * 64 + j * 16 + ln) * 72 + i * 16 + qd * 4] = pk;
            }
        __syncthreads();
        unsigned short* outp = (p == 0 ? Qp : Kp) + (size_t)(n * HEADS + h) * SEQ * HD + (size_t)s0 * HD;
        for (int i = 0; i < 8; ++i) {
            int idx = tid + i * 256;
            int row = idx >> 3, ch = idx & 7;
            *(uint4*)(outp + (size_t)row * HD + ch * 8) = *(const uint4*)&Xl[row * 72 + ch * 8];
        }
    } else {
#pragma unroll
        for (int mt = 0; mt < 4; ++mt)
#pragma unroll
            for (int i = 0; i < 4; ++i) {
                acc[mt][i] = __builtin_amdgcn_mfma_f32_16x16x32_bf16(a[mt][0], b[i][0], acc[mt][i], 0, 0, 0);
                acc[mt][i] = __builtin_amdgcn_mfma_f32_16x16x32_bf16(a[mt][1], b[i][1], acc[mt][i], 0, 0, 0);
            }
        __syncthreads();
#pragma unroll
        for (int mt = 0; mt < 4; ++mt)
#pragma unroll
            for (int i = 0; i < 4; ++i) {
                uint2 pk;
                pk.x = pack2(acc[mt][i][0], acc[mt][i][1]);
                pk.y = pack2(acc[mt][i][2], acc[mt][i][3]);
                *(uint2*)&Xl[(i * 16 + ln) * 264 + w * 64 + mt * 16 + qd * 4] = pk;
            }
        __syncthreads();
        unsigned short* outp = Vt + (size_t)(n * HEADS + h) * HD * SEQ + s0;
        for (int i = 0; i < 8; ++i) {
            int idx = tid + i * 256;
            int row = idx >> 5, ch = idx & 31;
            *(uint4*)(outp + (size_t)row * SEQ + ch * 8) = *(const uint4*)&Xl[row * 264 + ch * 8];
        }
    }
}

// ------------------------------------------------------------ flash attention
// Round-0 kernel, verbatim (best measured: 92.5-93.4 us). 32x32x16 MFMAs.
// S^T = K Q^T (C: col=q, row=key). P stays in registers; the PV B-fragment is
// assembled with v_permlane32_swap (shfl_xor fallback).
__global__ __launch_bounds__(512, 4) void attn_kernel(
    const unsigned short* __restrict__ Qp, const unsigned short* __restrict__ Kp,
    const unsigned short* __restrict__ Vt, unsigned short* __restrict__ Xattn)
{
    __shared__ __align__(16) unsigned short SMEM[18432];   // 36,864 B
    unsigned short* Kl = SMEM;           // [2][64*72]  (key, d)
    unsigned short* Vl = SMEM + 9216;    // [2][64*72]  (d, key)

    int bx = blockIdx.x;                 // 512 blocks: head*8 + qtile
    int head = bx >> 3, qt = bx & 7;
    int n = head >> 4, h16 = head & 15;
    int q0 = qt * 256;

    int tid = threadIdx.x;
    int w = tid >> 6, lane = tid & 63;
    int qc = lane & 31, hh = lane >> 5;

    const unsigned short* Qb = Qp + (size_t)head * SEQ * HD;
    const unsigned short* Kb = Kp + (size_t)head * SEQ * HD;
    const unsigned short* Vb = Vt + (size_t)head * HD * SEQ;

    // Q as B-operand (32x32x16): lane n=q, k(d) = kk*16 + hh*8 + j
    bf16x8 qb[4];
    {
        int qrow = q0 + w * 32 + qc;
#pragma unroll
        for (int kk = 0; kk < 4; ++kk)
            qb[kk] = *(const bf16x8*)(Qb + (size_t)qrow * HD + kk * 16 + hh * 8);
    }

    f32x16 ot0, ot1;
#pragma unroll
    for (int i = 0; i < 16; ++i) { ot0[i] = 0.f; ot1[i] = 0.f; }
    float ls[4] = {0.f, 0.f, 0.f, 0.f};     // 4-way partials, independent chains

    int srow = tid >> 3, sch = tid & 7;      // staging: 64 rows x 8 chunks

    // prologue: chunk 0 -> regs -> buf0 ; chunk 1 -> regs
    uint4 rK, rV;
    rK = *(const uint4*)(Kb + (size_t)srow * HD + sch * 8);
    rV = *(const uint4*)(Vb + (size_t)srow * SEQ + 0 + sch * 8);
    *(uint4*)&Kl[srow * 72 + sch * 8] = rK;
    *(uint4*)&Vl[srow * 72 + sch * 8] = rV;
    rK = *(const uint4*)(Kb + (size_t)(64 + srow) * HD + sch * 8);
    rV = *(const uint4*)(Vb + (size_t)srow * SEQ + 64 + sch * 8);

    for (int kc = 0; kc < SEQ; kc += 64) {
        int cur = (kc >> 6) & 1, nxt = cur ^ 1;
        int curo = cur * 4608;
        __syncthreads();   // chunk kc staged+visible; prior reads of buf[nxt] done

        if (kc + 64 < SEQ) {
            *(uint4*)&Kl[nxt * 4608 + srow * 72 + sch * 8] = rK;
            *(uint4*)&Vl[nxt * 4608 + srow * 72 + sch * 8] = rV;
            int kn = kc + 128 <= SEQ - 64 ? kc + 128 : SEQ - 64;
            rK = *(const uint4*)(Kb + (size_t)(kn + srow) * HD + sch * 8);
            rV = *(const uint4*)(Vb + (size_t)srow * SEQ + kn + sch * 8);
        }

        // ---- S^T = K Q^T (32x32 tiles), exp2, pack to bf16 pairs in regs
        unsigned pk[2][8];
#pragma unroll
        for (int kt = 0; kt < 2; ++kt) {
            f32x16 c;
#pragma unroll
            for (int i = 0; i < 16; ++i) c[i] = 0.f;
#pragma unroll
            for (int kk = 0; kk < 4; ++kk) {
                bf16x8 ka = *(const bf16x8*)&Kl[curo + (kt * 32 + qc) * 72 + kk * 16 + hh * 8];
                c = __builtin_amdgcn_mfma_f32_32x32x16_bf16(ka, qb[kk], c, 0, 0, 0);
            }
#pragma unroll
            for (int i = 0; i < 8; ++i) {
                float p0 = __builtin_amdgcn_exp2f(c[2 * i]);
                float p1 = __builtin_amdgcn_exp2f(c[2 * i + 1]);
                ls[i & 3] += p0 + p1;
                pk[kt][i] = pack2(p0, p1);
            }
        }

        // ---- O^T += V^T P^T : assemble B-frag per 16-key block
#pragma unroll
        for (int g = 0; g < 4; ++g) {
            const unsigned* P = pk[g >> 1];
            int base = (g & 1) * 4;
            union { unsigned u[4]; bf16x8 v; } bb;
#if __has_builtin(__builtin_amdgcn_permlane32_swap)
            uint2v r  = __builtin_amdgcn_permlane32_swap(P[base + 0], P[base + 2], false, false);
            uint2v rr = __builtin_amdgcn_permlane32_swap(P[base + 1], P[base + 3], false, false);
            bb.u[0] = r.x;
            bb.u[1] = rr.x;
            bb.u[2] = r.y;
            bb.u[3] = rr.y;
#else
            unsigned s0 = hh ? P[base + 0] : P[base + 2];
            unsigned s1 = hh ? P[base + 1] : P[base + 3];
            unsigned r0 = (unsigned)__shfl_xor((int)s0, 32);
            unsigned r1 = (unsigned)__shfl_xor((int)s1, 32);
            bb.u[0] = hh ? r0 : P[base + 0];
            bb.u[1] = hh ? r1 : P[base + 1];
            bb.u[2] = hh ? P[base + 2] : r0;
            bb.u[3] = hh ? P[base + 3] : r1;
#endif
            bf16x8 va0 = *(const bf16x8*)&Vl[curo + qc * 72 + g * 16 + hh * 8];
            bf16x8 va1 = *(const bf16x8*)&Vl[curo + (32 + qc) * 72 + g * 16 + hh * 8];
            ot0 = __builtin_amdgcn_mfma_f32_32x32x16_bf16(va0, bb.v, ot0, 0, 0, 0);
            ot1 = __builtin_amdgcn_mfma_f32_32x32x16_bf16(va1, bb.v, ot1, 0, 0, 0);
        }
    }

    // ---- finish l (combine partials, then the xor-32 partner half)
    float lsum = (ls[0] + ls[1]) + (ls[2] + ls[3]);
    lsum += __shfl_xor(lsum, 32);
    float inv = 1.0f / lsum;

    // ---- stage O [q][d] into SMEM (reuses K/V space), coalesced store
    __syncthreads();
    int qlocal = w * 32 + qc;
#pragma unroll
    for (int dt = 0; dt < 2; ++dt) {
        const f32x16& o = dt ? ot1 : ot0;
#pragma unroll
        for (int g = 0; g < 4; ++g) {
            uint2 p;
            p.x = pack2(o[4 * g + 0] * inv, o[4 * g + 1] * inv);
            p.y = pack2(o[4 * g + 2] * inv, o[4 * g + 3] * inv);
            *(uint2*)&SMEM[qlocal * 72 + dt * 32 + g * 8 + hh * 4] = p;
        }
    }
    __syncthreads();
    unsigned short* ob = Xattn + (size_t)(n * SEQ + q0) * EMBED + h16 * HD;
#pragma unroll
    for (int i = 0; i < 4; ++i) {
        int idx = tid + i * 512;                 // 256 rows x 8 chunks
        int row = idx >> 3, ch = idx & 7;
        *(uint4*)(ob + (size_t)row * EMBED + ch * 8) = *(const uint4*)&SMEM[row * 72 + ch * 8];
    }
}

// ----------------------------------------------------- out = Xattn@Wo^T + bo
// Original 64x128-tile version (present in the lowest measured total, 264.4):
// grid 1024 -> 4-5 blocks/CU (16-20 waves/CU) — cross-block TLP hides the
// synchronous K-loop's staging latency.  LDS 27.6 KB.
__global__ __launch_bounds__(256, 4) void outproj_kernel(
    const unsigned short* __restrict__ X, const unsigned short* __restrict__ Wb,
    const float* __restrict__ bo, float* __restrict__ out)
{
    __shared__ __align__(16) unsigned short Al[64 * 72];
    __shared__ __align__(16) unsigned short Bl[128 * 72];

    int bx = blockIdx.x;                 // 1024 = 128 row-tiles x 8 col-tiles
    int cm = bx >> 3, cn = bx & 7;
    int m0 = cm * 64, c0 = cn * 128;
    int tid = threadIdx.x;
    int w = tid >> 6, lane = tid & 63, ln = lane & 15, qd = lane >> 4;
    int chw = w * 32;                    // wave's 32-col slice

    f32x4 acc[4][2];
    const f32x4 fz = {0.f, 0.f, 0.f, 0.f};
#pragma unroll
    for (int mt = 0; mt < 4; ++mt)
#pragma unroll
        for (int nt = 0; nt < 2; ++nt) acc[mt][nt] = fz;

    for (int k0 = 0; k0 < EMBED; k0 += 64) {
#pragma unroll
        for (int i = 0; i < 2; ++i) {
            int idx = tid + i * 256;          // 512 uint4
            int r2 = idx >> 3, c2 = idx & 7;
            uint4 av = *(const uint4*)(X + (size_t)(m0 + r2) * EMBED + k0 + c2 * 8);
            *(uint4*)&Al[r2 * 72 + c2 * 8] = av;
        }
#pragma unroll
        for (int i = 0; i < 4; ++i) {
            int idx = tid + i * 256;          // 1024 uint4
            int r2 = idx >> 3, c2 = idx & 7;
            uint4 bv = *(const uint4*)(Wb + (size_t)(c0 + r2) * EMBED + k0 + c2 * 8);
            *(uint4*)&Bl[r2 * 72 + c2 * 8] = bv;
        }
        __syncthreads();
        bf16x8 af[4][2], bf_[2][2];
#pragma unroll
        for (int mt = 0; mt < 4; ++mt)
#pragma unroll
            for (int kt = 0; kt < 2; ++kt)
                af[mt][kt] = *(const bf16x8*)&Al[(mt * 16 + ln) * 72 + kt * 32 + qd * 8];
#pragma unroll
        for (int nt = 0; nt < 2; ++nt)
#pragma unroll
            for (int kt = 0; kt < 2; ++kt)
                bf_[nt][kt] = *(const bf16x8*)&Bl[(chw + nt * 16 + ln) * 72 + kt * 32 + qd * 8];
#pragma unroll
        for (int mt = 0; mt < 4; ++mt)
#pragma unroll
            for (int nt = 0; nt < 2; ++nt) {
                acc[mt][nt] = __builtin_amdgcn_mfma_f32_16x16x32_bf16(af[mt][0], bf_[nt][0], acc[mt][nt], 0, 0, 0);
                acc[mt][nt] = __builtin_amdgcn_mfma_f32_16x16x32_bf16(af[mt][1], bf_[nt][1], acc[mt][nt], 0, 0, 0);
            }
        __syncthreads();
    }

#pragma unroll
    for (int nt = 0; nt < 2; ++nt) {
        int col = c0 + chw + nt * 16 + ln;
        float bias = bo[col];
#pragma unroll
        for (int mt = 0; mt < 4; ++mt) {
            int row = m0 + mt * 16 + qd * 4;
#pragma unroll
            for (int rg = 0; rg < 4; ++rg)
                out[(size_t)(row + rg) * EMBED + col] = acc[mt][nt][rg] + bias;
        }
    }
}

// --------------------------------------------------------------------- launch
extern "C" void kernel_launch(void* const* d_in, const int* in_sizes, int n_in,
                              void* d_out, int out_size, void* d_ws, size_t ws_size,
                              hipStream_t stream) {
    const float* values = (const float*)d_in[0];
    const float* keys   = (const float*)d_in[1];
    const float* query  = (const float*)d_in[2];
    const float* Wv     = (const float*)d_in[3];
    const float* Wk     = (const float*)d_in[4];
    const float* Wq     = (const float*)d_in[5];
    const float* Wo     = (const float*)d_in[6];
    const float* bo     = (const float*)d_in[7];
    float* out = (float*)d_out;

    unsigned short* ws = (unsigned short*)d_ws;
    const size_t HSZ = (size_t)NB * HEADS * SEQ * HD;   // 8388608 elems
    unsigned short* Qp = ws;
    unsigned short* Kp = Qp + HSZ;
    unsigned short* Vt = Kp + HSZ;
    unsigned short* Xa = Vt + HSZ;
    unsigned short* Wb = Xa + HSZ;                       // 1024*1024 elems

    proj_kernel<<<1792, 256, 0, stream>>>(query, keys, values, Wq, Wk, Wv,
                                          Wo, (unsigned*)Wb, Qp, Kp, Vt);
    attn_kernel<<<512, 512, 0, stream>>>(Qp, Kp, Vt, Xa);
    outproj_kernel<<<1024, 256, 0, stream>>>(Xa, Wb, bo, out);
}